// Round 5
// baseline (96.438 us; speedup 1.0000x reference)
//
#include <hip/hip_runtime.h>

#define Bn 8
#define Cc 64
#define CO 64
#define Hh 128
#define Ww 128
#define Kk 9
#define HW (Hh*Ww)

typedef __attribute__((ext_vector_type(8))) short bf16x8;
typedef __attribute__((ext_vector_type(4))) float f32x4;

__device__ __forceinline__ short f2bf(float f) {
    unsigned u = __float_as_uint(f);
    u = (u + 0x7FFFu + ((u >> 16) & 1u)) >> 16;   // RNE
    return (short)u;
}

__device__ __forceinline__ unsigned cvt_pk_bf16(float lo, float hi) {
    unsigned d;
    asm("v_cvt_pk_bf16_f32 %0, %1, %2" : "=v"(d) : "v"(lo), "v"(hi));
    return d;
}

// ---------------- kernel 1: input NCHW fp32 -> NHWC bf16 ----------------
__global__ __launch_bounds__(256) void transpose_in_kernel(
    const float* __restrict__ in, short* __restrict__ in_t)
{
    __shared__ float tile[64 * 65];
    int bid  = blockIdx.x;          // B*H*2 = 2048
    int xblk = bid & 1;
    int row  = bid >> 1;            // b*H + y
    int y    = row & (Hh - 1);
    int b    = row >> 7;
    int x0   = xblk << 6;
    int t    = threadIdx.x;

    int x  = t & 63;
    int cq = t >> 6;
    const float* src = in + (size_t)b * Cc * HW + (size_t)y * Ww + x0;
#pragma unroll
    for (int i = 0; i < 16; ++i) {
        int c = cq * 16 + i;
        tile[c * 65 + x] = src[(size_t)c * HW + x];
    }
    __syncthreads();
    int c2 = t & 63;
    int xq = t >> 6;
    short* dst = in_t + ((size_t)(b * Hh + y) * Ww + x0) * Cc;
#pragma unroll
    for (int i = 0; i < 16; ++i) {
        int xx = xq * 16 + i;
        dst[(size_t)xx * Cc + c2] = f2bf(tile[c2 * 65 + xx]);
    }
}

// ---------------- kernel 2: weight fp32 [co][c][k] -> bf16 [k][co][c] ----------------
__global__ __launch_bounds__(256) void prep_w_kernel(
    const float* __restrict__ w, short* __restrict__ w_t)
{
    int idx = blockIdx.x * 256 + threadIdx.x;
    if (idx < Kk * CO * Cc) {
        int k  = idx >> 12;
        int co = (idx >> 6) & 63;
        int c  = idx & 63;
        w_t[idx] = f2bf(w[((size_t)co * Cc + c) * Kk + k]);
    }
}

// ---------------- kernel 3: fused sample + MFMA, register-direct B ----------------
// Sampling lane map == MFMA B-fragment map: px = 16*wv + (l&15), cgrp = l>>4.
// Blended samples feed MFMA directly from registers; no S tile in LDS.
__global__ __launch_bounds__(256, 4) void dcn_main_kernel(
    const short* __restrict__ in_t,   // [B][H][W][C] bf16
    const float* __restrict__ offm,   // [B][27][H][W] fp32
    const short* __restrict__ w_t,    // [K][CO][C] bf16
    const float* __restrict__ bias,   // [CO] fp32
    float* __restrict__ out)          // [B][CO][H][W] fp32
{
    __shared__ short s_W[2][64][72];  // weight bf16 [co][c], pad 72 (2-way only)

    int bid  = blockIdx.x;            // 2048
    int xblk = bid & 1;
    int row  = bid >> 1;
    int y    = row & (Hh - 1);
    int b    = row >> 7;
    int x0   = xblk << 6;
    int t    = threadIdx.x;
    int l    = t & 63;
    int wv   = t >> 6;                // wave 0..3
    int lm   = l & 15;                // px within wave stripe == MFMA col
    int g    = l >> 4;                // channel group == MFMA k-chunk
    int px   = (wv << 4) + lm;

    const float* offb = offm + (size_t)b * 27 * HW + (size_t)y * Ww + x0 + px;
    const short* inb  = in_t + (size_t)b * HW * Cc;

    // W staging indices (256 threads cover 64co x 64c)
    int wco = t >> 2;
    int wc0 = (t & 3) << 4;

    // preload all 27 per-pixel offset scalars (coalesced within quarter-waves)
    float offv[Kk][3];
#pragma unroll
    for (int k = 0; k < Kk; ++k) {
        offv[k][0] = offb[(size_t)(2 * k) * HW];
        offv[k][1] = offb[(size_t)(2 * k + 1) * HW];
        offv[k][2] = offb[(size_t)(18 + k) * HW];
    }

    f32x4 acc[4] = {{0.f,0.f,0.f,0.f},{0.f,0.f,0.f,0.f},{0.f,0.f,0.f,0.f},{0.f,0.f,0.f,0.f}};

    uint4 r[4][2];   // in-flight corner gathers [corner][half]
    uint4 wq[2];     // in-flight W slice
    float cw[4];     // corner weights (mask folded)

    auto stage_load = [&](int k) {
        // W slice FIRST: its ds_write then needs only vmcnt(8), not a full drain
        const uint4* wk = (const uint4*)(w_t + (size_t)k * (CO * Cc) + 16 * t);
        wq[0] = wk[0];
        wq[1] = wk[1];

        float dy = offv[k][0], dx = offv[k][1], ml = offv[k][2];
        float m  = __builtin_amdgcn_rcpf(1.0f + __expf(-ml));

        float ys = (float)(y + (k / 3) - 1) + dy;
        float xs = (float)(x0 + px + (k % 3) - 1) + dx;
        float yf = floorf(ys), xf = floorf(xs);
        int y0i = (int)yf, x0i = (int)xf;
        float wy = ys - yf, wx = xs - xf;

        bool vy0 = (unsigned)y0i < (unsigned)Hh;
        bool vy1 = (unsigned)(y0i + 1) < (unsigned)Hh;
        bool vx0 = (unsigned)x0i < (unsigned)Ww;
        bool vx1 = (unsigned)(x0i + 1) < (unsigned)Ww;

        int cy0 = min(max(y0i, 0), Hh - 1);
        int cy1 = min(max(y0i + 1, 0), Hh - 1);
        int cx0 = min(max(x0i, 0), Ww - 1);
        int cx1 = min(max(x0i + 1, 0), Ww - 1);

        cw[0] = (vy0 && vx0) ? (1.0f - wy) * (1.0f - wx) * m : 0.0f;
        cw[1] = (vy0 && vx1) ? (1.0f - wy) * wx * m : 0.0f;
        cw[2] = (vy1 && vx0) ? wy * (1.0f - wx) * m : 0.0f;
        cw[3] = (vy1 && vx1) ? wy * wx * m : 0.0f;

        int idx[4] = {cy0 * Ww + cx0, cy0 * Ww + cx1, cy1 * Ww + cx0, cy1 * Ww + cx1};
#pragma unroll
        for (int cc = 0; cc < 4; ++cc) {
            // 4 lanes (g=0..3) cover one aligned 64B half-row per px
            const short* p = inb + (size_t)idx[cc] * Cc + (g << 3);
            r[cc][0] = *(const uint4*)p;          // channels 8g   .. 8g+7
            r[cc][1] = *(const uint4*)(p + 32);   // channels 32+8g.. +7
        }
    };

    auto w_store = [&](int nb) {
        *(uint4*)&s_W[nb][wco][wc0]     = wq[0];
        *(uint4*)&s_W[nb][wco][wc0 + 8] = wq[1];
    };

    bf16x8 b0, b1;
    auto blend_pack = [&]() {
        float a0[8], a1[8];
#pragma unroll
        for (int j = 0; j < 8; ++j) { a0[j] = 0.0f; a1[j] = 0.0f; }
#pragma unroll
        for (int cc = 0; cc < 4; ++cc) {
            float w = cw[cc];
            unsigned q0[4] = {r[cc][0].x, r[cc][0].y, r[cc][0].z, r[cc][0].w};
            unsigned q1[4] = {r[cc][1].x, r[cc][1].y, r[cc][1].z, r[cc][1].w};
#pragma unroll
            for (int d = 0; d < 4; ++d) {
                a0[2*d]   = fmaf(w, __uint_as_float(q0[d] << 16),         a0[2*d]);
                a0[2*d+1] = fmaf(w, __uint_as_float(q0[d] & 0xffff0000u), a0[2*d+1]);
                a1[2*d]   = fmaf(w, __uint_as_float(q1[d] << 16),         a1[2*d]);
                a1[2*d+1] = fmaf(w, __uint_as_float(q1[d] & 0xffff0000u), a1[2*d+1]);
            }
        }
        union { unsigned d[4]; bf16x8 v; } p0, p1;
#pragma unroll
        for (int j = 0; j < 4; ++j) {
            p0.d[j] = cvt_pk_bf16(a0[2*j], a0[2*j+1]);
            p1.d[j] = cvt_pk_bf16(a1[2*j], a1[2*j+1]);
        }
        b0 = p0.v;
        b1 = p1.v;
    };

    // prologue
    stage_load(0);
    w_store(0);
    __syncthreads();

#pragma unroll
    for (int k = 0; k < Kk; ++k) {
        int cb = k & 1;
        blend_pack();                    // waits gathers(k); produces b0,b1
        if (k < Kk - 1) {
            stage_load(k + 1);           // issue W loads then gathers (reuses r,cw,wq)
            w_store(cb ^ 1);             // vmcnt(8): only W loads drained
        }
        // GEMM: out[co][px] += W^T[co][c] * B[c][px], K=64 per k
#pragma unroll
        for (int f = 0; f < 4; ++f) {
            bf16x8 A0 = *(const bf16x8*)&s_W[cb][(f << 4) + lm][(g << 3)];
            bf16x8 A1 = *(const bf16x8*)&s_W[cb][(f << 4) + lm][32 + (g << 3)];
            acc[f] = __builtin_amdgcn_mfma_f32_16x16x32_bf16(A0, b0, acc[f], 0, 0, 0);
            acc[f] = __builtin_amdgcn_mfma_f32_16x16x32_bf16(A1, b1, acc[f], 0, 0, 0);
        }
        if (k < Kk - 1) __syncthreads();
    }

    // epilogue: lane l holds D[co = 16f + 4g + rr][px = 16wv + lm]
    float* outb = out + (size_t)b * CO * HW + (size_t)y * Ww + x0 + (wv << 4) + lm;
#pragma unroll
    for (int f = 0; f < 4; ++f) {
#pragma unroll
        for (int rr = 0; rr < 4; ++rr) {
            int co = (f << 4) + (g << 2) + rr;
            outb[(size_t)co * HW] = acc[f][rr] + bias[co];
        }
    }
}

// ---------------- launcher ----------------
extern "C" void kernel_launch(void* const* d_in, const int* in_sizes, int n_in,
                              void* d_out, int out_size, void* d_ws, size_t ws_size,
                              hipStream_t stream)
{
    const float* in   = (const float*)d_in[0];
    const float* offm = (const float*)d_in[1];
    const float* w    = (const float*)d_in[2];
    const float* bias = (const float*)d_in[3];
    float* out = (float*)d_out;

    short* in_t = (short*)d_ws;                          // 8*128*128*64 bf16 = 16 MiB
    short* w_t  = in_t + (size_t)Bn * HW * Cc;           // 9*64*64 bf16 = 72 KiB

    transpose_in_kernel<<<Bn * Hh * 2, 256, 0, stream>>>(in, in_t);
    prep_w_kernel<<<(Kk * CO * Cc + 255) / 256, 256, 0, stream>>>(w, w_t);
    dcn_main_kernel<<<Bn * Hh * 2, 256, 0, stream>>>(in_t, offm, w_t, bias, out);
}